// Round 10
// baseline (98.950 us; speedup 1.0000x reference)
//
#include <hip/hip_runtime.h>

#define SEQ   2048
#define HALF  1024          // tokens gathered per block (2 blocks/row)
#define EMB   100
#define BOT   5
#define HSIZE 4096          // power of two, 2*SEQ slots, <=50% load factor
#define FT    1024          // threads per block (16 waves)
#define NW    16

// ---------------- kA: histogram + double-row float4 gather ----------------
// Two blocks per row. cnt*idf = idf + (cnt-1)*idf: pass-1 gathers with weight
// idf (from LDS), pass-2 adds rare (cnt-1)*idf corrections. One float4 load
// fetches TWO token rows (lanes 0..24 row i, lanes 25..49 row i+1): 32 gather
// instructions per wave instead of 64+64. 1/Z applied in kB.
// Determinism: fixed partitions and reduce orders; race-invariant counts;
// lane-ordered ballot fixup; both half-blocks write identical Z bits.
__global__ __launch_bounds__(FT) void kA_fused(
    const int* __restrict__ x, const float* __restrict__ idf,
    const float* __restrict__ we, float* __restrict__ partial,
    float* __restrict__ zfull)
{
    __shared__ int   hkey[HSIZE];
    __shared__ int   hcnt[HSIZE];
    __shared__ int   skey[SEQ];
    __shared__ float sidf[SEQ];
    __shared__ float sdup[HALF];
    __shared__ float part[NW][2][EMB];
    __shared__ float zred[NW];

    const int bx = blockIdx.x, b = bx >> 1, half = bx & 1;
    const int tid = threadIdx.x, lane = tid & 63, wid = tid >> 6;

    for (int i = tid; i < HSIZE; i += FT) { hkey[i] = -1; hcnt[i] = 0; }
    skey[tid]        = x[(size_t)b * SEQ + tid];
    skey[tid + HALF] = x[(size_t)b * SEQ + tid + HALF];
    __syncthreads();

    // issue idf gathers first; they stay in flight during the LDS histogram
    const int   k0 = skey[tid], k1 = skey[tid + HALF];
    const float w0 = idf[k0],   w1 = idf[k1];

    unsigned slot0 = ((unsigned)k0 * 2654435761u) >> 20;
    for (;;) {
        int prev = atomicCAS(&hkey[slot0], -1, k0);
        if (prev == -1 || prev == k0) { atomicAdd(&hcnt[slot0], 1); break; }
        slot0 = (slot0 + 1) & (HSIZE - 1);
    }
    unsigned slot1 = ((unsigned)k1 * 2654435761u) >> 20;
    for (;;) {
        int prev = atomicCAS(&hkey[slot1], -1, k1);
        if (prev == -1 || prev == k1) { atomicAdd(&hcnt[slot1], 1); break; }
        slot1 = (slot1 + 1) & (HSIZE - 1);
    }

    sidf[tid] = w0;  sidf[tid + HALF] = w1;

    float z = w0 + w1;                                   // fixed-order Z
    for (int off = 32; off > 0; off >>= 1) z += __shfl_down(z, off);
    if (lane == 0) zred[wid] = z;
    __syncthreads();                 // histogram + sidf complete; counts final

    // duplicate-correction weight for this half's token of this thread
    {
        const int   ms = half ? (int)slot1 : (int)slot0;
        const float mw = half ? w1 : w0;
        const int   c  = hcnt[ms];
        sdup[tid] = (c > 1) ? (float)(c - 1) * mw : 0.0f;
    }
    if (tid == 0) {
        float t = 0.0f;
        #pragma unroll
        for (int i = 0; i < NW; ++i) t += zred[i];
        zfull[b] = t;                // both halves: identical bits
    }
    __syncthreads();

    // ---- pass-1 gather: wave w owns local tokens [w*64, w*64+64) ----
    const int  hb  = half * HALF;
    const bool act = (lane < 50);
    const int  sub = (lane < 25) ? 0 : 1;     // which token of the pair
    const int  q   = (lane < 25) ? lane : lane - 25;   // float4 index 0..24

    float4 a0={0,0,0,0}, a1={0,0,0,0}, a2={0,0,0,0}, a3={0,0,0,0};
    float4 a4={0,0,0,0}, a5={0,0,0,0}, a6={0,0,0,0}, a7={0,0,0,0};

    if (act) {
        const int t0 = hb + wid * 64 + sub;
        #pragma unroll
        for (int it = 0; it < 4; ++it) {
            const int base = t0 + it * 16;     // 8 pairs = 16 tokens / iter
            int   kk0 = skey[base+ 0], kk1 = skey[base+ 2], kk2 = skey[base+ 4], kk3 = skey[base+ 6];
            int   kk4 = skey[base+ 8], kk5 = skey[base+10], kk6 = skey[base+12], kk7 = skey[base+14];
            float ww0 = sidf[base+ 0], ww1 = sidf[base+ 2], ww2 = sidf[base+ 4], ww3 = sidf[base+ 6];
            float ww4 = sidf[base+ 8], ww5 = sidf[base+10], ww6 = sidf[base+12], ww7 = sidf[base+14];
            float4 v0 = ((const float4*)(we + (size_t)kk0 * EMB))[q];
            float4 v1 = ((const float4*)(we + (size_t)kk1 * EMB))[q];
            float4 v2 = ((const float4*)(we + (size_t)kk2 * EMB))[q];
            float4 v3 = ((const float4*)(we + (size_t)kk3 * EMB))[q];
            float4 v4 = ((const float4*)(we + (size_t)kk4 * EMB))[q];
            float4 v5 = ((const float4*)(we + (size_t)kk5 * EMB))[q];
            float4 v6 = ((const float4*)(we + (size_t)kk6 * EMB))[q];
            float4 v7 = ((const float4*)(we + (size_t)kk7 * EMB))[q];
            a0.x+=ww0*v0.x; a0.y+=ww0*v0.y; a0.z+=ww0*v0.z; a0.w+=ww0*v0.w;
            a1.x+=ww1*v1.x; a1.y+=ww1*v1.y; a1.z+=ww1*v1.z; a1.w+=ww1*v1.w;
            a2.x+=ww2*v2.x; a2.y+=ww2*v2.y; a2.z+=ww2*v2.z; a2.w+=ww2*v2.w;
            a3.x+=ww3*v3.x; a3.y+=ww3*v3.y; a3.z+=ww3*v3.z; a3.w+=ww3*v3.w;
            a4.x+=ww4*v4.x; a4.y+=ww4*v4.y; a4.z+=ww4*v4.z; a4.w+=ww4*v4.w;
            a5.x+=ww5*v5.x; a5.y+=ww5*v5.y; a5.z+=ww5*v5.z; a5.w+=ww5*v5.w;
            a6.x+=ww6*v6.x; a6.y+=ww6*v6.y; a6.z+=ww6*v6.z; a6.w+=ww6*v6.w;
            a7.x+=ww7*v7.x; a7.y+=ww7*v7.y; a7.z+=ww7*v7.z; a7.w+=ww7*v7.w;
        }
    }

    // ---- pass-2: rare duplicate corrections, lane order (fixed) ----
    {
        float sd = sdup[wid * 64 + lane];
        int   kl = skey[hb + wid * 64 + lane];
        unsigned long long m = __ballot(sd != 0.0f);
        while (m) {
            int src = __ffsll((long long)m) - 1;  m &= m - 1;
            float wv = __shfl(sd, src);
            int   kv = __shfl(kl, src);
            if (lane < 25) {                      // corrections go to sub=0 partial
                float4 v = ((const float4*)(we + (size_t)kv * EMB))[q];
                a0.x += wv*v.x; a0.y += wv*v.y; a0.z += wv*v.z; a0.w += wv*v.w;
            }
        }
    }

    if (act) {
        float4 s;
        s.x = ((a0.x+a1.x)+(a2.x+a3.x)) + ((a4.x+a5.x)+(a6.x+a7.x));
        s.y = ((a0.y+a1.y)+(a2.y+a3.y)) + ((a4.y+a5.y)+(a6.y+a7.y));
        s.z = ((a0.z+a1.z)+(a2.z+a3.z)) + ((a4.z+a5.z)+(a6.z+a7.z));
        s.w = ((a0.w+a1.w)+(a2.w+a3.w)) + ((a4.w+a5.w)+(a6.w+a7.w));
        ((float4*)part[wid][sub])[q] = s;         // 400B rows, 16B aligned
    }
    __syncthreads();

    if (tid < EMB) {
        float a = 0.0f;
        #pragma unroll
        for (int w = 0; w < NW; ++w) a += part[w][0][tid] + part[w][1][tid];
        partial[(size_t)bx * EMB + tid] = a;      // fixed order
    }
}

// ---------------- kB: combine halves, apply 1/Z, tiny MLP ----------------
__global__ __launch_bounds__(128) void kB_mlp(
    const float* __restrict__ partial, const float* __restrict__ zfull,
    const float* __restrict__ fc1w, const float* __restrict__ fc1b,
    const float* __restrict__ fc2w, const float* __restrict__ fc2b,
    float* __restrict__ out)
{
    __shared__ float doc[EMB];
    __shared__ float hsh[BOT];

    const int b = blockIdx.x, tid = threadIdx.x;
    const float iz = 1.0f / zfull[b];

    if (tid < EMB) {
        const float* p = partial + (size_t)b * 2 * EMB + tid;
        doc[tid] = (p[0] + p[EMB]) * iz;          // fixed order
    }
    __syncthreads();

    if (tid < BOT) {
        float h = fc1b[tid];
        const float* wr = fc1w + tid * EMB;
        for (int e = 0; e < EMB; ++e) h += doc[e] * wr[e];
        hsh[tid] = h;
    }
    __syncthreads();

    if (tid < EMB) {
        float o = fc2b[tid];
        const float* wr = fc2w + tid * BOT;
        #pragma unroll
        for (int j = 0; j < BOT; ++j) o += hsh[j] * wr[j];
        out[(size_t)b * EMB + tid] = o;
    }
}

extern "C" void kernel_launch(void* const* d_in, const int* in_sizes, int n_in,
                              void* d_out, int out_size, void* d_ws, size_t ws_size,
                              hipStream_t stream) {
    const int*   x    = (const int*)d_in[0];
    const float* we   = (const float*)d_in[1];
    const float* idf  = (const float*)d_in[2];
    const float* fc1w = (const float*)d_in[3];
    const float* fc1b = (const float*)d_in[4];
    const float* fc2w = (const float*)d_in[5];
    const float* fc2b = (const float*)d_in[6];
    float*       out  = (float*)d_out;

    const int B = in_sizes[0] / SEQ;  // 128

    char*  ws      = (char*)d_ws;
    float* zfull   = (float*)ws;                 // B floats
    float* partial = (float*)(ws + 4096);        // B*2*EMB floats (~102 KB)

    kA_fused<<<B * 2, FT,  0, stream>>>(x, idf, we, partial, zfull);
    kB_mlp  <<<B,     128, 0, stream>>>(partial, zfull, fc1w, fc1b, fc2w, fc2b, out);
}